// Round 7
// baseline (82080.273 us; speedup 1.0000x reference)
//
#include <hip/hip_runtime.h>
#include <math.h>

// Problem constants
#define HH    1028        // real hidden size
#define TT    16384       // timesteps
#define UP    1056        // padded hidden (= 16*66 = 8*132)
#define HSU   1056        // (val,tag) u64 pairs per ring row
#define HS    1056        // floats per h2 history row
#define NWG0  66          // layer-0 WGs, 16 units each
#define NWG1  132         // layer-1 WGs, 8 units each
#define NWGT  (NWG0 + NWG1)
#define R0    1024        // h1 ring depth
#define R0M   (R0 - 1)
#define R1M   15          // h2 ring depth 16

typedef unsigned long long u64;
typedef unsigned int uint4v __attribute__((ext_vector_type(4)));

// ---------- MALL-coherent primitives ----------
__device__ __forceinline__ u64 ld_u64(const u64* p) {
    return __hip_atomic_load(p, __ATOMIC_RELAXED, __HIP_MEMORY_SCOPE_AGENT);
}
__device__ __forceinline__ void st_u64(u64* p, u64 v) {
    __hip_atomic_store(p, v, __ATOMIC_RELAXED, __HIP_MEMORY_SCOPE_AGENT);
}
__device__ __forceinline__ unsigned ld_u32(const unsigned* p) {
    return __hip_atomic_load(p, __ATOMIC_RELAXED, __HIP_MEMORY_SCOPE_AGENT);
}
__device__ __forceinline__ void st_u32(unsigned* p, unsigned v) {
    __hip_atomic_store(p, v, __ATOMIC_RELAXED, __HIP_MEMORY_SCOPE_AGENT);
}
__device__ __forceinline__ float sigmf(float x) { return 1.0f / (1.0f + expf(-x)); }
__device__ __forceinline__ u64 pack(unsigned tag, float v) {
    return ((u64)tag << 32) | (u64)__float_as_uint(v);
}

// ---------- LDS slice-ready flags (replace barrier A) ----------
// Stager sets flag[s]=tag (release) after its slice is in LDS; compute waves
// acquire-spin until flag >= tag. Tags are monotone (1..16385), no resets.
__device__ __forceinline__ void set_flag(unsigned* f, unsigned v) {
    __hip_atomic_store(f, v, __ATOMIC_RELEASE, __HIP_MEMORY_SCOPE_WORKGROUP);
}
__device__ __forceinline__ void wait_flag(unsigned* f, unsigned want, long long& budget) {
    for (;;) {
        unsigned v = __hip_atomic_load(f, __ATOMIC_ACQUIRE, __HIP_MEMORY_SCOPE_WORKGROUP);
        if ((int)v >= (int)want) break;
        if (--budget < 0) break;          // hang safety valve
    }
}

// 16B coherent poll load: two (val,tag) pairs per request (r4-verified win).
#define POLL16(dst, ptr) \
    asm volatile("global_load_dwordx4 %0, %1, off sc0 sc1" : "=v"(dst) : "v"(ptr))

// Stage 132 (val,tag) pairs [base, base+132) into LDS via 66 x 16B polls.
__device__ __forceinline__ void stage132w(const u64* __restrict__ src, float* __restrict__ lds,
                                          int base, int lane, unsigned want, long long& budget) {
    const u64* p0 = src + base + 2 * lane;          // chunk lane      (all 64)
    const u64* p1 = src + base + 2 * (64 + lane);   // chunk 64+lane   (lanes 0-1)
    bool d0 = false, d1 = (lane >= 2);
    uint4v r0 = {0, 0, 0, 0}, r1 = {0, 0, 0, 0};
    int spin = 2;
    for (;;) {
        if (!d0) POLL16(r0, p0);
        if (!d1) POLL16(r1, p1);
        asm volatile("s_waitcnt vmcnt(0)" ::: "memory");
        __builtin_amdgcn_sched_barrier(0);          // no reg-only hoist past waitcnt
        if (!d0 && r0[1] == want && r0[3] == want) {
            *(float2*)&lds[base + 2 * lane] =
                make_float2(__uint_as_float(r0[0]), __uint_as_float(r0[2]));
            d0 = true;
        }
        if (!d1 && r1[1] == want && r1[3] == want) {
            *(float2*)&lds[base + 2 * (64 + lane)] =
                make_float2(__uint_as_float(r1[0]), __uint_as_float(r1[2]));
            d1 = true;
        }
        if (__all(d0 & d1)) break;
        if (--budget < 0) break;          // hang safety valve
        if (spin > 0) { --spin; continue; }
        __builtin_amdgcn_s_sleep(1);
    }
}

// Stage 264 pairs [base, base+264) via 132 x 16B polls.
__device__ __forceinline__ void stage264w(const u64* __restrict__ src, float* __restrict__ lds,
                                          int base, int lane, unsigned want, long long& budget) {
    const u64* p0 = src + base + 2 * lane;
    const u64* p1 = src + base + 2 * (64 + lane);
    const u64* p2 = src + base + 2 * (128 + lane);  // lanes 0-3
    bool d0 = false, d1 = false, d2 = (lane >= 4);
    uint4v r0 = {0, 0, 0, 0}, r1 = {0, 0, 0, 0}, r2 = {0, 0, 0, 0};
    int spin = 2;
    for (;;) {
        if (!d0) POLL16(r0, p0);
        if (!d1) POLL16(r1, p1);
        if (!d2) POLL16(r2, p2);
        asm volatile("s_waitcnt vmcnt(0)" ::: "memory");
        __builtin_amdgcn_sched_barrier(0);
        if (!d0 && r0[1] == want && r0[3] == want) {
            *(float2*)&lds[base + 2 * lane] =
                make_float2(__uint_as_float(r0[0]), __uint_as_float(r0[2]));
            d0 = true;
        }
        if (!d1 && r1[1] == want && r1[3] == want) {
            *(float2*)&lds[base + 2 * (64 + lane)] =
                make_float2(__uint_as_float(r1[0]), __uint_as_float(r1[2]));
            d1 = true;
        }
        if (!d2 && r2[1] == want && r2[3] == want) {
            *(float2*)&lds[base + 2 * (128 + lane)] =
                make_float2(__uint_as_float(r2[0]), __uint_as_float(r2[2]));
            d2 = true;
        }
        if (__all(d0 & d1 & d2)) break;
        if (--budget < 0) break;
        if (spin > 0) { --spin; continue; }
        __builtin_amdgcn_s_sleep(1);
    }
}

// ---------- fused 2-layer LSTM recurrence ----------
// Structure = r4 (verified 40.7ms) with ONE change: barrier A replaced by
// per-slice LDS tag-flags, so compute stripe m starts as soon as the staged
// entries it reads have arrived -> compute overlaps the detect straggler tail.
__global__ __launch_bounds__(1024, 4) void wn_fused(
    const float* __restrict__ x,
    const float* __restrict__ w_ih0, const float* __restrict__ w_hh0,
    const float* __restrict__ b_ih0, const float* __restrict__ b_hh0,
    const float* __restrict__ w_ih1, const float* __restrict__ w_hh1,
    const float* __restrict__ b_ih1, const float* __restrict__ b_hh1,
    u64* __restrict__ ring0,                  // [R0][HSU] (val,tag) of h1
    u64* __restrict__ ring1,                  // [16][HSU] (val,tag) of h2
    float* __restrict__ h2hist,               // [TT][HS] plain h2 for projection
    unsigned* __restrict__ l1prog)            // L1 WG0 progress (poison-tolerant)
{
    __shared__ float smem[4 * UP + 160];
    const int tid  = threadIdx.x;
    const int lane = tid & 63;
    const int w    = tid >> 6;                // wave 0..15

    for (int i = tid; i < 4 * UP + 160; i += 1024) smem[i] = 0.0f;

    if (blockIdx.x < NWG0) {
        // ========== layer 0 : 16 units/WG, rows = 4 gates x 16 units, 16 lanes/row ==========
        float* hbuf = smem;                   // [2][UP] staged h1
        float* gbuf = smem + 2 * UP;          // [2][64] gate pre-activations
        unsigned* hflg = (unsigned*)(smem + 4 * UP + 128);  // [8] slice flags
        const int wg   = blockIdx.x;
        const int row  = tid >> 4;            // 0..63 = gate*16 + du
        const int k0   = tid & 15;
        const int gate = row >> 4;
        const int du   = row & 15;
        const int u    = wg * 16 + du;
        const bool real = (u < HH);
        const int wr   = gate * HH + (real ? u : 0);

        float wv[16][4], wt0 = 0.f, wt1 = 0.f;
#pragma unroll
        for (int m = 0; m < 16; ++m) {
            const int j = k0 * 4 + m * 64;
#pragma unroll
            for (int q = 0; q < 4; ++q)
                wv[m][q] = (real && j + q < HH) ? w_hh0[(size_t)wr * HH + j + q] : 0.0f;
        }
        {   const int j = 1024 + k0 * 2;
            wt0 = (real && j     < HH) ? w_hh0[(size_t)wr * HH + j]     : 0.0f;
            wt1 = (real && j + 1 < HH) ? w_hh0[(size_t)wr * HH + j + 1] : 0.0f; }
#pragma unroll
        for (int m = 0; m < 16; ++m)
#pragma unroll
            for (int q = 0; q < 4; ++q) asm volatile("" : "+v"(wv[m][q]));
        asm volatile("" : "+v"(wt0), "+v"(wt1));

        const float wx = real ? w_ih0[wr] : 0.0f;
        const float bs = real ? (b_ih0[wr] + b_hh0[wr]) : 0.0f;
        __syncthreads();

        long long budget = 20000000LL;
        float c_reg = 0.0f;
        for (int t = 0; t < TT; ++t) {
            // ---- phase P: epilogue+publish(t-1) [wave0] || poll+stage h1(t-1) [waves4-11] ----
            if (t > 0) {
                if (w == 0) {
                    const float* gl = gbuf + ((t - 1) & 1) * 64;
                    if (lane < 16) {
                        const float gi = gl[lane], gf = gl[16 + lane];
                        const float gg = gl[32 + lane], go = gl[48 + lane];
                        const float iv = sigmf(gi), fv = sigmf(gf), gv = tanhf(gg), ov = sigmf(go);
                        c_reg = fv * c_reg + iv * gv;
                        float hv = ov * tanhf(c_reg);
                        if (wg * 16 + lane >= HH) hv = 0.0f;
                        st_u64(ring0 + (size_t)((t - 1) & R0M) * HSU + wg * 16 + lane,
                               pack((unsigned)t, hv));      // coalesced 128B burst
                    }
                } else if (w >= 4 && w < 12) {
                    stage132w(ring0 + (size_t)((t - 1) & R0M) * HSU, hbuf + (t & 1) * UP,
                              (w - 4) * 132, lane, (unsigned)t, budget);
                    if (lane == 0) set_flag(&hflg[w - 4], (unsigned)t);
                } else if (w == 1 && lane == 0 && (t & 255) == 0) {
                    for (;;) {                 // ring backpressure: never lap L1
                        unsigned p = ld_u32(l1prog);
                        if ((int)t - (int)p < R0 - 256) break;
                        if (--budget < 0) break;
                        __builtin_amdgcn_s_sleep(32);
                    }
                }
            }
            // (no barrier A) compute stripes gated by slice flags
            const float* hb = hbuf + (t & 1) * UP;
            float acc = 0.0f;
#pragma unroll
            for (int m = 0; m < 16; ++m) {
                if ((m & 1) == 0 && t > 0)
                    wait_flag(&hflg[m >> 1], (unsigned)t, budget);
                const float4 hv = *(const float4*)&hb[k0 * 4 + m * 64];
                acc = fmaf(wv[m][0], hv.x, acc);
                acc = fmaf(wv[m][1], hv.y, acc);
                acc = fmaf(wv[m][2], hv.z, acc);
                acc = fmaf(wv[m][3], hv.w, acc);
            }
            {   const float2 hv = *(const float2*)&hb[1024 + k0 * 2];
                acc = fmaf(wt0, hv.x, acc);
                acc = fmaf(wt1, hv.y, acc); }
#pragma unroll
            for (int off = 1; off < 16; off <<= 1) acc += __shfl_xor(acc, off);
            if (k0 == 0) gbuf[(t & 1) * 64 + row] = acc + x[t] * wx + bs;
            __syncthreads();                   // B: gates visible for next P
        }
        // final epilogue+publish for t = TT-1
        if (w == 0 && lane < 16) {
            const float* gl = gbuf + ((TT - 1) & 1) * 64;
            const float gi = gl[lane], gf = gl[16 + lane];
            const float gg = gl[32 + lane], go = gl[48 + lane];
            const float iv = sigmf(gi), fv = sigmf(gf), gv = tanhf(gg), ov = sigmf(go);
            c_reg = fv * c_reg + iv * gv;
            float hv = ov * tanhf(c_reg);
            if (wg * 16 + lane >= HH) hv = 0.0f;
            st_u64(ring0 + (size_t)((TT - 1) & R0M) * HSU + wg * 16 + lane,
                   pack((unsigned)TT, hv));
        }
    } else {
        // ========== layer 1 : 8 units/WG, rows = 4 gates x 8 units, 32 lanes/row ==========
        float* abuf = smem;                   // [2][UP] h1[t]
        float* bbuf = smem + 2 * UP;          // [2][UP] h2[t-1]
        float* gbuf = smem + 4 * UP;          // [2][32]
        unsigned* bflg = (unsigned*)(smem + 4 * UP + 128);  // [8] bbuf slice flags
        unsigned* aflg = bflg + 8;                          // [4] abuf slice flags
        const int wg   = blockIdx.x - NWG0;   // 0..131
        const int row  = tid >> 5;            // 0..31 = gate*8 + du
        const int k0   = tid & 31;
        const int gate = row >> 3;
        const int du   = row & 7;
        const int u    = wg * 8 + du;
        const bool real = (u < HH);
        const int wr   = gate * HH + (real ? u : 0);

        float wiv[8][4], whv[8][4], wit = 0.f, wht = 0.f;
#pragma unroll
        for (int m = 0; m < 8; ++m) {
            const int j = k0 * 4 + m * 128;
#pragma unroll
            for (int q = 0; q < 4; ++q) {
                const bool inb = real && (j + q < HH);
                wiv[m][q] = inb ? w_ih1[(size_t)wr * HH + j + q] : 0.0f;
                whv[m][q] = inb ? w_hh1[(size_t)wr * HH + j + q] : 0.0f;
            }
        }
        {   const int j = 1024 + k0;
            wit = (real && j < HH) ? w_ih1[(size_t)wr * HH + j] : 0.0f;
            wht = (real && j < HH) ? w_hh1[(size_t)wr * HH + j] : 0.0f; }
#pragma unroll
        for (int m = 0; m < 8; ++m)
#pragma unroll
            for (int q = 0; q < 4; ++q) {
                asm volatile("" : "+v"(wiv[m][q]));
                asm volatile("" : "+v"(whv[m][q]));
            }
        asm volatile("" : "+v"(wit), "+v"(wht));
        const float bs = real ? (b_ih1[wr] + b_hh1[wr]) : 0.0f;
        __syncthreads();

        long long budget = 20000000LL;
        float c_reg = 0.0f;
        for (int t = 0; t < TT; ++t) {
            // ---- phase P: epilogue(t-1) [wave0] || stage h2(t-1) [w4-11] || stage h1(t) [w12-15] ----
            if (w == 0) {
                if (t > 0) {
                    const float* gl = gbuf + ((t - 1) & 1) * 32;
                    if (lane < 8) {
                        const float gi = gl[lane], gf = gl[8 + lane];
                        const float gg = gl[16 + lane], go = gl[24 + lane];
                        const float iv = sigmf(gi), fv = sigmf(gf), gv = tanhf(gg), ov = sigmf(go);
                        c_reg = fv * c_reg + iv * gv;
                        float hv = ov * tanhf(c_reg);
                        if (wg * 8 + lane >= HH) hv = 0.0f;
                        st_u64(ring1 + (size_t)((t - 1) & R1M) * HSU + wg * 8 + lane,
                               pack((unsigned)t, hv));     // coalesced 64B burst
                        h2hist[(size_t)(t - 1) * HS + wg * 8 + lane] = hv;
                    }
                }
            } else if (w >= 4 && w < 12) {
                if (t > 0) {
                    stage132w(ring1 + (size_t)((t - 1) & R1M) * HSU, bbuf + (t & 1) * UP,
                              (w - 4) * 132, lane, (unsigned)t, budget);
                    if (lane == 0) set_flag(&bflg[w - 4], (unsigned)t);
                }
            } else if (w >= 12) {
                stage264w(ring0 + (size_t)(t & R0M) * HSU, abuf + (t & 1) * UP,
                          (w - 12) * 264, lane, (unsigned)(t + 1), budget);
                if (lane == 0) set_flag(&aflg[w - 12], (unsigned)(t + 1));
            }
            // (no barrier A) compute stripes gated by slice flags
            const float* ab = abuf + (t & 1) * UP;
            const float* bb = bbuf + (t & 1) * UP;
            float acc = 0.0f;
#pragma unroll
            for (int m = 0; m < 8; ++m) {
                if (t > 0) wait_flag(&bflg[m], (unsigned)t, budget);
                if ((m & 1) == 0) wait_flag(&aflg[m >> 1], (unsigned)(t + 1), budget);
                const float4 ha = *(const float4*)&ab[k0 * 4 + m * 128];
                const float4 hb2 = *(const float4*)&bb[k0 * 4 + m * 128];
                acc = fmaf(wiv[m][0], ha.x, acc);
                acc = fmaf(wiv[m][1], ha.y, acc);
                acc = fmaf(wiv[m][2], ha.z, acc);
                acc = fmaf(wiv[m][3], ha.w, acc);
                acc = fmaf(whv[m][0], hb2.x, acc);
                acc = fmaf(whv[m][1], hb2.y, acc);
                acc = fmaf(whv[m][2], hb2.z, acc);
                acc = fmaf(whv[m][3], hb2.w, acc);
            }
            acc = fmaf(wit, ab[1024 + k0], acc);
            acc = fmaf(wht, bb[1024 + k0], acc);
#pragma unroll
            for (int off = 1; off < 32; off <<= 1) acc += __shfl_xor(acc, off);
            if (k0 == 0) gbuf[(t & 1) * 32 + row] = acc + bs;
            __syncthreads();                   // B
            if (w == 1 && lane == 0 && wg == 0 && (t & 255) == 255)
                st_u32(l1prog, (unsigned)(t + 1));        // backpressure progress
        }
        // final epilogue for t = TT-1
        if (w == 0 && lane < 8) {
            const float* gl = gbuf + ((TT - 1) & 1) * 32;
            const float gi = gl[lane], gf = gl[8 + lane];
            const float gg = gl[16 + lane], go = gl[24 + lane];
            const float iv = sigmf(gi), fv = sigmf(gf), gv = tanhf(gg), ov = sigmf(go);
            c_reg = fv * c_reg + iv * gv;
            float hv = ov * tanhf(c_reg);
            if (wg * 8 + lane >= HH) hv = 0.0f;
            h2hist[(size_t)(TT - 1) * HS + wg * 8 + lane] = hv;
        }
    }
}

// ---------- final projection: out[t] = lin_w . h2[t] + lin_b ----------
__global__ __launch_bounds__(256) void wn_proj(
    const float* __restrict__ h2,
    const float* __restrict__ lin_w,
    const float* __restrict__ lin_b,
    float* __restrict__ out)
{
    const int lane = threadIdx.x & 63;
    const int wv   = threadIdx.x >> 6;
    const int t    = blockIdx.x * 4 + wv;
    const float* hp = h2 + (size_t)t * HS;
    float acc = 0.0f;
#pragma unroll
    for (int m = 0; m < 4; ++m) {
        const int j = lane * 4 + m * 256;        // covers [0,1024)
        const float4 h4 = *(const float4*)(hp + j);
        const float4 w4 = *(const float4*)(lin_w + j);
        acc += h4.x * w4.x + h4.y * w4.y + h4.z * w4.z + h4.w * w4.w;
    }
    if (lane == 0) {
#pragma unroll
        for (int j = 1024; j < HH; ++j) acc += hp[j] * lin_w[j];
    }
#pragma unroll
    for (int off = 1; off < 64; off <<= 1) acc += __shfl_xor(acc, off);
    if (lane == 0) out[t] = acc + lin_b[0];
}

extern "C" void kernel_launch(void* const* d_in, const int* in_sizes, int n_in,
                              void* d_out, int out_size, void* d_ws, size_t ws_size,
                              hipStream_t stream) {
    const float* x     = (const float*)d_in[0];
    const float* w_ih0 = (const float*)d_in[1];
    const float* w_hh0 = (const float*)d_in[2];
    const float* b_ih0 = (const float*)d_in[3];
    const float* b_hh0 = (const float*)d_in[4];
    const float* w_ih1 = (const float*)d_in[5];
    const float* w_hh1 = (const float*)d_in[6];
    const float* b_ih1 = (const float*)d_in[7];
    const float* b_hh1 = (const float*)d_in[8];
    const float* lin_w = (const float*)d_in[9];
    const float* lin_b = (const float*)d_in[10];
    float* out = (float*)d_out;

    char* ws = (char*)d_ws;
    const size_t R0B = (size_t)R0 * HSU * 8;        //  8,650,752
    const size_t R1B = (size_t)16 * HSU * 8;        //    135,168
    const size_t H2B = (size_t)TT * HS * 4;         // 69,206,016
    u64* ring0 = (u64*)(ws);
    u64* ring1 = (u64*)(ws + R0B);
    float* h2hist = (float*)(ws + R0B + R1B);
    unsigned* l1prog = (unsigned*)(ws + R0B + R1B + H2B);
    // No init kernel: 0xAA poison never matches any tag (1..16384), and the
    // poisoned l1prog reads as negative -> L0 throttles until L1 publishes.

    wn_fused<<<NWGT, 1024, 0, stream>>>(x, w_ih0, w_hh0, b_ih0, b_hh0,
                                        w_ih1, w_hh1, b_ih1, b_hh1,
                                        ring0, ring1, h2hist, l1prog);
    wn_proj<<<TT / 4, 256, 0, stream>>>(h2hist, lin_w, lin_b, out);
}

// Round 8
// 45344.830 us; speedup vs baseline: 1.8101x; 1.8101x over previous
//
#include <hip/hip_runtime.h>
#include <math.h>

// Problem constants
#define HH    1028        // real hidden size
#define TT    16384       // timesteps
#define UP    1056        // padded hidden (= 16*66 = 8*132)
#define HSU   1056        // (val,tag) u64 pairs per ring row
#define HS    1056        // floats per h2 history row
#define NWG0  66          // layer-0 WGs, 16 units each
#define NWG1  132         // layer-1 WGs, 8 units each
#define NWGT  (NWG0 + NWG1)
#define R0    1024        // h1 ring depth
#define R0M   (R0 - 1)
#define R1M   15          // h2 ring depth 16

typedef unsigned long long u64;
typedef unsigned int uint4v __attribute__((ext_vector_type(4)));

// ---------- MALL-coherent primitives ----------
__device__ __forceinline__ u64 ld_u64(const u64* p) {
    return __hip_atomic_load(p, __ATOMIC_RELAXED, __HIP_MEMORY_SCOPE_AGENT);
}
__device__ __forceinline__ void st_u64(u64* p, u64 v) {
    __hip_atomic_store(p, v, __ATOMIC_RELAXED, __HIP_MEMORY_SCOPE_AGENT);
}
__device__ __forceinline__ unsigned ld_u32(const unsigned* p) {
    return __hip_atomic_load(p, __ATOMIC_RELAXED, __HIP_MEMORY_SCOPE_AGENT);
}
__device__ __forceinline__ void st_u32(unsigned* p, unsigned v) {
    __hip_atomic_store(p, v, __ATOMIC_RELAXED, __HIP_MEMORY_SCOPE_AGENT);
}
__device__ __forceinline__ float sigmf(float x) { return 1.0f / (1.0f + expf(-x)); }
__device__ __forceinline__ u64 pack(unsigned tag, float v) {
    return ((u64)tag << 32) | (u64)__float_as_uint(v);
}

// 16B coherent poll load: two (val,tag) pairs per request (r4-verified win).
#define POLL16(dst, ptr) \
    asm volatile("global_load_dwordx4 %0, %1, off sc0 sc1" : "=v"(dst) : "v"(ptr))

// Stage 176 (val,tag) pairs [base, base+176): 88 chunks (p0 all, p1 lanes<24).
__device__ __forceinline__ void stage176w(const u64* __restrict__ src, float* __restrict__ lds,
                                          int base, int lane, unsigned want, long long& budget) {
    const u64* p0 = src + base + 2 * lane;
    const u64* p1 = src + base + 2 * (64 + lane);
    bool d0 = false, d1 = (lane >= 24);
    uint4v r0 = {0, 0, 0, 0}, r1 = {0, 0, 0, 0};
    int spin = 2;
    for (;;) {
        if (!d0) POLL16(r0, p0);
        if (!d1) POLL16(r1, p1);
        asm volatile("s_waitcnt vmcnt(0)" ::: "memory");
        __builtin_amdgcn_sched_barrier(0);
        if (!d0 && r0[1] == want && r0[3] == want) {
            *(float2*)&lds[base + 2 * lane] =
                make_float2(__uint_as_float(r0[0]), __uint_as_float(r0[2]));
            d0 = true;
        }
        if (!d1 && r1[1] == want && r1[3] == want) {
            *(float2*)&lds[base + 2 * (64 + lane)] =
                make_float2(__uint_as_float(r1[0]), __uint_as_float(r1[2]));
            d1 = true;
        }
        if (__all(d0 & d1)) break;
        if (--budget < 0) break;          // hang safety valve
        if (spin > 0) { --spin; continue; }
        __builtin_amdgcn_s_sleep(1);
    }
}

// Stage 352 pairs [base, base+352): 176 chunks (p0, p1 all; p2 lanes<48).
__device__ __forceinline__ void stage352w(const u64* __restrict__ src, float* __restrict__ lds,
                                          int base, int lane, unsigned want, long long& budget) {
    const u64* p0 = src + base + 2 * lane;
    const u64* p1 = src + base + 2 * (64 + lane);
    const u64* p2 = src + base + 2 * (128 + lane);
    bool d0 = false, d1 = false, d2 = (lane >= 48);
    uint4v r0 = {0, 0, 0, 0}, r1 = {0, 0, 0, 0}, r2 = {0, 0, 0, 0};
    int spin = 2;
    for (;;) {
        if (!d0) POLL16(r0, p0);
        if (!d1) POLL16(r1, p1);
        if (!d2) POLL16(r2, p2);
        asm volatile("s_waitcnt vmcnt(0)" ::: "memory");
        __builtin_amdgcn_sched_barrier(0);
        if (!d0 && r0[1] == want && r0[3] == want) {
            *(float2*)&lds[base + 2 * lane] =
                make_float2(__uint_as_float(r0[0]), __uint_as_float(r0[2]));
            d0 = true;
        }
        if (!d1 && r1[1] == want && r1[3] == want) {
            *(float2*)&lds[base + 2 * (64 + lane)] =
                make_float2(__uint_as_float(r1[0]), __uint_as_float(r1[2]));
            d1 = true;
        }
        if (!d2 && r2[1] == want && r2[3] == want) {
            *(float2*)&lds[base + 2 * (128 + lane)] =
                make_float2(__uint_as_float(r2[0]), __uint_as_float(r2[2]));
            d2 = true;
        }
        if (__all(d0 & d1 & d2)) break;
        if (--budget < 0) break;
        if (spin > 0) { --spin; continue; }
        __builtin_amdgcn_s_sleep(1);
    }
}

// ---------- fused 2-layer LSTM recurrence ----------
// r4 phase structure (verified 40.7ms): phase P (epilogue+publish || staging),
// barrier A, compute, barrier B, same publish bursts/rings/tags/parity.
// Change: 512-thread WGs -> 256 regs/lane -> each lane holds ALL 4 gates'
// weights for its k-slice -> LDS read traffic drops ~3.6x (the ~3400cy
// LDS-serialized compute phase was the dominant non-comm term).
__global__ __launch_bounds__(512, 2) void wn_fused(
    const float* __restrict__ x,
    const float* __restrict__ w_ih0, const float* __restrict__ w_hh0,
    const float* __restrict__ b_ih0, const float* __restrict__ b_hh0,
    const float* __restrict__ w_ih1, const float* __restrict__ w_hh1,
    const float* __restrict__ b_ih1, const float* __restrict__ b_hh1,
    u64* __restrict__ ring0,                  // [R0][HSU] (val,tag) of h1
    u64* __restrict__ ring1,                  // [16][HSU] (val,tag) of h2
    float* __restrict__ h2hist,               // [TT][HS] plain h2 for projection
    unsigned* __restrict__ l1prog)            // L1 WG0 progress (poison-tolerant)
{
    __shared__ float smem[4 * UP + 128];
    const int tid  = threadIdx.x;
    const int lane = tid & 63;
    const int w    = tid >> 6;                // wave 0..7

    for (int i = tid; i < 4 * UP + 128; i += 512) smem[i] = 0.0f;

    if (blockIdx.x < NWG0) {
        // ===== layer 0: wave w computes units wg*16 + {2w, 2w+1} (one per half-wave).
        //       32 k-lanes/unit; lane holds 4 gates x 33 weights = 132. =====
        float* hbuf = smem;                   // [2][UP] staged h1
        float* gbuf = smem + 2 * UP;          // [2][64] gate pre-activations (g*16+du)
        const int wg   = blockIdx.x;
        const int hi   = lane >> 5;           // half-wave
        const int k0   = lane & 31;
        const int du   = w * 2 + hi;
        const int u    = wg * 16 + du;
        const bool real = (u < HH);

        float wv[4][8][4], wt4[4], wx4[4], bs4[4];
#pragma unroll
        for (int g = 0; g < 4; ++g) {
            const int wr = g * HH + (real ? u : 0);
#pragma unroll
            for (int m = 0; m < 8; ++m) {
                const int j = k0 * 4 + m * 128;     // <= 1023, always < HH
#pragma unroll
                for (int q = 0; q < 4; ++q)
                    wv[g][m][q] = real ? w_hh0[(size_t)wr * HH + j + q] : 0.0f;
            }
            const int jt = 1024 + k0;
            wt4[g] = (real && jt < HH) ? w_hh0[(size_t)wr * HH + jt] : 0.0f;
            wx4[g] = real ? w_ih0[wr] : 0.0f;
            bs4[g] = real ? (b_ih0[wr] + b_hh0[wr]) : 0.0f;
        }
#pragma unroll
        for (int g = 0; g < 4; ++g)
#pragma unroll
            for (int m = 0; m < 8; ++m)
#pragma unroll
                for (int q = 0; q < 4; ++q) asm volatile("" : "+v"(wv[g][m][q]));
        __syncthreads();

        long long budget = 20000000LL;
        float c_reg = 0.0f;                   // wave0 lanes<16: per-unit cell state
        for (int t = 0; t < TT; ++t) {
            // ---- phase P: epilogue+publish(t-1) [wave0] || stage h1(t-1) [waves2-7] ----
            if (t > 0) {
                if (w == 0) {
                    const float* gl = gbuf + ((t - 1) & 1) * 64;
                    if (lane < 16) {
                        const float gi = gl[lane], gf = gl[16 + lane];
                        const float gg = gl[32 + lane], go = gl[48 + lane];
                        const float iv = sigmf(gi), fv = sigmf(gf), gv = tanhf(gg), ov = sigmf(go);
                        c_reg = fv * c_reg + iv * gv;
                        float hv = ov * tanhf(c_reg);
                        if (wg * 16 + lane >= HH) hv = 0.0f;
                        st_u64(ring0 + (size_t)((t - 1) & R0M) * HSU + wg * 16 + lane,
                               pack((unsigned)t, hv));      // coalesced 128B burst
                    }
                } else if (w >= 2) {
                    stage176w(ring0 + (size_t)((t - 1) & R0M) * HSU, hbuf + (t & 1) * UP,
                              (w - 2) * 176, lane, (unsigned)t, budget);
                } else if (w == 1 && lane == 0 && (t & 255) == 0) {
                    for (;;) {                 // ring backpressure: never lap L1
                        unsigned p = ld_u32(l1prog);
                        if ((int)t - (int)p < R0 - 256) break;
                        if (--budget < 0) break;
                        __builtin_amdgcn_s_sleep(32);
                    }
                }
            }
            __syncthreads();                   // A: stage visible
            const float* hb = hbuf + (t & 1) * UP;
            float acc[4] = {0.f, 0.f, 0.f, 0.f};
#pragma unroll
            for (int m = 0; m < 8; ++m) {
                const float4 hv4 = *(const float4*)&hb[k0 * 4 + m * 128];
#pragma unroll
                for (int g = 0; g < 4; ++g) {
                    acc[g] = fmaf(wv[g][m][0], hv4.x, acc[g]);
                    acc[g] = fmaf(wv[g][m][1], hv4.y, acc[g]);
                    acc[g] = fmaf(wv[g][m][2], hv4.z, acc[g]);
                    acc[g] = fmaf(wv[g][m][3], hv4.w, acc[g]);
                }
            }
            {   const float ht = hb[1024 + k0];
#pragma unroll
                for (int g = 0; g < 4; ++g) acc[g] = fmaf(wt4[g], ht, acc[g]); }
            // 32-lane butterflies (xor<32 stays within the half-wave)
#pragma unroll
            for (int off = 1; off < 32; off <<= 1) {
#pragma unroll
                for (int g = 0; g < 4; ++g) acc[g] += __shfl_xor(acc[g], off);
            }
            if (k0 == 0) {
                const float xt = x[t];
                float* gw = gbuf + (t & 1) * 64;
#pragma unroll
                for (int g = 0; g < 4; ++g)
                    gw[g * 16 + du] = fmaf(xt, wx4[g], acc[g]) + bs4[g];
            }
            __syncthreads();                   // B: gates visible for next P
        }
        // final epilogue+publish for t = TT-1
        if (w == 0 && lane < 16) {
            const float* gl = gbuf + ((TT - 1) & 1) * 64;
            const float gi = gl[lane], gf = gl[16 + lane];
            const float gg = gl[32 + lane], go = gl[48 + lane];
            const float iv = sigmf(gi), fv = sigmf(gf), gv = tanhf(gg), ov = sigmf(go);
            c_reg = fv * c_reg + iv * gv;
            float hv = ov * tanhf(c_reg);
            if (wg * 16 + lane >= HH) hv = 0.0f;
            st_u64(ring0 + (size_t)((TT - 1) & R0M) * HSU + wg * 16 + lane,
                   pack((unsigned)TT, hv));
        }
    } else {
        // ===== layer 1: wave w computes unit wg*8 + w; 64 k-lanes/unit;
        //       lane holds 4 gates x (16 ih + 16 hh + tails) = 136 weights. =====
        float* abuf = smem;                   // [2][UP] h1[t]
        float* bbuf = smem + 2 * UP;          // [2][UP] h2[t-1]
        float* gbuf = smem + 4 * UP;          // [2][32] (g*8+du)
        const int wg   = blockIdx.x - NWG0;   // 0..131
        const int du   = w;
        const int u    = wg * 8 + du;
        const bool real = (u < HH);

        float wiv[4][4][4], whv[4][4][4], wti4[4], wth4[4], bs4[4];
#pragma unroll
        for (int g = 0; g < 4; ++g) {
            const int wr = g * HH + (real ? u : 0);
#pragma unroll
            for (int m = 0; m < 4; ++m) {
                const int j = lane * 4 + m * 256;   // <= 1023, always < HH
#pragma unroll
                for (int q = 0; q < 4; ++q) {
                    wiv[g][m][q] = real ? w_ih1[(size_t)wr * HH + j + q] : 0.0f;
                    whv[g][m][q] = real ? w_hh1[(size_t)wr * HH + j + q] : 0.0f;
                }
            }
            const int jt = 1024 + lane;
            const bool inb = real && lane < 32 && jt < HH;
            wti4[g] = inb ? w_ih1[(size_t)wr * HH + jt] : 0.0f;
            wth4[g] = inb ? w_hh1[(size_t)wr * HH + jt] : 0.0f;
            bs4[g]  = real ? (b_ih1[wr] + b_hh1[wr]) : 0.0f;
        }
#pragma unroll
        for (int g = 0; g < 4; ++g)
#pragma unroll
            for (int m = 0; m < 4; ++m)
#pragma unroll
                for (int q = 0; q < 4; ++q) {
                    asm volatile("" : "+v"(wiv[g][m][q]));
                    asm volatile("" : "+v"(whv[g][m][q]));
                }
        __syncthreads();

        long long budget = 20000000LL;
        float c_reg = 0.0f;                   // wave0 lanes<8: per-unit cell state
        for (int t = 0; t < TT; ++t) {
            // ---- phase P: epilogue(t-1) [wave0] || stage h2(t-1) [w2-4] || stage h1(t) [w5-7] ----
            if (w == 0) {
                if (t > 0) {
                    const float* gl = gbuf + ((t - 1) & 1) * 32;
                    if (lane < 8) {
                        const float gi = gl[lane], gf = gl[8 + lane];
                        const float gg = gl[16 + lane], go = gl[24 + lane];
                        const float iv = sigmf(gi), fv = sigmf(gf), gv = tanhf(gg), ov = sigmf(go);
                        c_reg = fv * c_reg + iv * gv;
                        float hv = ov * tanhf(c_reg);
                        if (wg * 8 + lane >= HH) hv = 0.0f;
                        st_u64(ring1 + (size_t)((t - 1) & R1M) * HSU + wg * 8 + lane,
                               pack((unsigned)t, hv));     // coalesced 64B burst
                        h2hist[(size_t)(t - 1) * HS + wg * 8 + lane] = hv;
                    }
                }
            } else if (w >= 2 && w < 5) {
                if (t > 0)
                    stage352w(ring1 + (size_t)((t - 1) & R1M) * HSU, bbuf + (t & 1) * UP,
                              (w - 2) * 352, lane, (unsigned)t, budget);
            } else if (w >= 5) {
                stage352w(ring0 + (size_t)(t & R0M) * HSU, abuf + (t & 1) * UP,
                          (w - 5) * 352, lane, (unsigned)(t + 1), budget);
            }
            __syncthreads();                   // A
            const float* ab = abuf + (t & 1) * UP;
            const float* bb = bbuf + (t & 1) * UP;
            float acc[4] = {0.f, 0.f, 0.f, 0.f};
#pragma unroll
            for (int m = 0; m < 4; ++m) {
                const float4 ha = *(const float4*)&ab[lane * 4 + m * 256];
                const float4 hc = *(const float4*)&bb[lane * 4 + m * 256];
#pragma unroll
                for (int g = 0; g < 4; ++g) {
                    acc[g] = fmaf(wiv[g][m][0], ha.x, acc[g]);
                    acc[g] = fmaf(wiv[g][m][1], ha.y, acc[g]);
                    acc[g] = fmaf(wiv[g][m][2], ha.z, acc[g]);
                    acc[g] = fmaf(wiv[g][m][3], ha.w, acc[g]);
                    acc[g] = fmaf(whv[g][m][0], hc.x, acc[g]);
                    acc[g] = fmaf(whv[g][m][1], hc.y, acc[g]);
                    acc[g] = fmaf(whv[g][m][2], hc.z, acc[g]);
                    acc[g] = fmaf(whv[g][m][3], hc.w, acc[g]);
                }
            }
            if (lane < 32) {
                const float ha = ab[1024 + lane];
                const float hc = bb[1024 + lane];
#pragma unroll
                for (int g = 0; g < 4; ++g) {
                    acc[g] = fmaf(wti4[g], ha, acc[g]);
                    acc[g] = fmaf(wth4[g], hc, acc[g]);
                }
            }
            // full-wave butterflies
#pragma unroll
            for (int off = 1; off < 64; off <<= 1) {
#pragma unroll
                for (int g = 0; g < 4; ++g) acc[g] += __shfl_xor(acc[g], off);
            }
            if (lane == 0) {
                float* gw = gbuf + (t & 1) * 32;
#pragma unroll
                for (int g = 0; g < 4; ++g) gw[g * 8 + du] = acc[g] + bs4[g];
            }
            __syncthreads();                   // B
            if (w == 1 && lane == 0 && wg == 0 && (t & 255) == 255)
                st_u32(l1prog, (unsigned)(t + 1));        // backpressure progress
        }
        // final epilogue for t = TT-1
        if (w == 0 && lane < 8) {
            const float* gl = gbuf + ((TT - 1) & 1) * 32;
            const float gi = gl[lane], gf = gl[8 + lane];
            const float gg = gl[16 + lane], go = gl[24 + lane];
            const float iv = sigmf(gi), fv = sigmf(gf), gv = tanhf(gg), ov = sigmf(go);
            c_reg = fv * c_reg + iv * gv;
            float hv = ov * tanhf(c_reg);
            if (wg * 8 + lane >= HH) hv = 0.0f;
            h2hist[(size_t)(TT - 1) * HS + wg * 8 + lane] = hv;
        }
    }
}

// ---------- final projection: out[t] = lin_w . h2[t] + lin_b ----------
__global__ __launch_bounds__(256) void wn_proj(
    const float* __restrict__ h2,
    const float* __restrict__ lin_w,
    const float* __restrict__ lin_b,
    float* __restrict__ out)
{
    const int lane = threadIdx.x & 63;
    const int wv   = threadIdx.x >> 6;
    const int t    = blockIdx.x * 4 + wv;
    const float* hp = h2 + (size_t)t * HS;
    float acc = 0.0f;
#pragma unroll
    for (int m = 0; m < 4; ++m) {
        const int j = lane * 4 + m * 256;        // covers [0,1024)
        const float4 h4 = *(const float4*)(hp + j);
        const float4 w4 = *(const float4*)(lin_w + j);
        acc += h4.x * w4.x + h4.y * w4.y + h4.z * w4.z + h4.w * w4.w;
    }
    if (lane == 0) {
#pragma unroll
        for (int j = 1024; j < HH; ++j) acc += hp[j] * lin_w[j];
    }
#pragma unroll
    for (int off = 1; off < 64; off <<= 1) acc += __shfl_xor(acc, off);
    if (lane == 0) out[t] = acc + lin_b[0];
}

extern "C" void kernel_launch(void* const* d_in, const int* in_sizes, int n_in,
                              void* d_out, int out_size, void* d_ws, size_t ws_size,
                              hipStream_t stream) {
    const float* x     = (const float*)d_in[0];
    const float* w_ih0 = (const float*)d_in[1];
    const float* w_hh0 = (const float*)d_in[2];
    const float* b_ih0 = (const float*)d_in[3];
    const float* b_hh0 = (const float*)d_in[4];
    const float* w_ih1 = (const float*)d_in[5];
    const float* w_hh1 = (const float*)d_in[6];
    const float* b_ih1 = (const float*)d_in[7];
    const float* b_hh1 = (const float*)d_in[8];
    const float* lin_w = (const float*)d_in[9];
    const float* lin_b = (const float*)d_in[10];
    float* out = (float*)d_out;

    char* ws = (char*)d_ws;
    const size_t R0B = (size_t)R0 * HSU * 8;        //  8,650,752
    const size_t R1B = (size_t)16 * HSU * 8;        //    135,168
    const size_t H2B = (size_t)TT * HS * 4;         // 69,206,016
    u64* ring0 = (u64*)(ws);
    u64* ring1 = (u64*)(ws + R0B);
    float* h2hist = (float*)(ws + R0B + R1B);
    unsigned* l1prog = (unsigned*)(ws + R0B + R1B + H2B);
    // No init kernel: 0xAA poison never matches any tag (1..16384), and the
    // poisoned l1prog reads as negative -> L0 throttles until L1 publishes.

    wn_fused<<<NWGT, 512, 0, stream>>>(x, w_ih0, w_hh0, b_ih0, b_hh0,
                                       w_ih1, w_hh1, b_ih1, b_hh1,
                                       ring0, ring1, h2hist, l1prog);
    wn_proj<<<TT / 4, 256, 0, stream>>>(h2hist, lin_w, lin_b, out);
}

// Round 9
// 40583.975 us; speedup vs baseline: 2.0225x; 1.1173x over previous
//
#include <hip/hip_runtime.h>
#include <math.h>

// Problem constants
#define HH    1028        // real hidden size
#define TT    16384       // timesteps
#define UP    1056        // padded hidden (= 16*66 = 8*132)
#define HSU   1056        // (val,tag) u64 pairs per ring row
#define HS    1056        // floats per h2 history row
#define NWG0  66          // layer-0 WGs, 16 units each
#define NWG1  132         // layer-1 WGs, 8 units each
#define NWGT  (NWG0 + NWG1)
#define R0    1024        // h1 ring depth
#define R0M   (R0 - 1)
#define R1M   15          // h2 ring depth 16

typedef unsigned long long u64;
typedef unsigned int uint4v __attribute__((ext_vector_type(4)));

// ---------- MALL-coherent primitives ----------
__device__ __forceinline__ u64 ld_u64(const u64* p) {
    return __hip_atomic_load(p, __ATOMIC_RELAXED, __HIP_MEMORY_SCOPE_AGENT);
}
__device__ __forceinline__ void st_u64(u64* p, u64 v) {
    __hip_atomic_store(p, v, __ATOMIC_RELAXED, __HIP_MEMORY_SCOPE_AGENT);
}
__device__ __forceinline__ unsigned ld_u32(const unsigned* p) {
    return __hip_atomic_load(p, __ATOMIC_RELAXED, __HIP_MEMORY_SCOPE_AGENT);
}
__device__ __forceinline__ void st_u32(unsigned* p, unsigned v) {
    __hip_atomic_store(p, v, __ATOMIC_RELAXED, __HIP_MEMORY_SCOPE_AGENT);
}
__device__ __forceinline__ float sigmf(float x) { return 1.0f / (1.0f + expf(-x)); }
__device__ __forceinline__ u64 pack(unsigned tag, float v) {
    return ((u64)tag << 32) | (u64)__float_as_uint(v);
}

// 16B coherent poll load: two (val,tag) pairs per request (r4-verified win).
#define POLL16(dst, ptr) \
    asm volatile("global_load_dwordx4 %0, %1, off sc0 sc1" : "=v"(dst) : "v"(ptr))

// Stage 132 (val,tag) pairs [base, base+132) into LDS via 66 x 16B polls.
__device__ __forceinline__ void stage132w(const u64* __restrict__ src, float* __restrict__ lds,
                                          int base, int lane, unsigned want, long long& budget) {
    const u64* p0 = src + base + 2 * lane;          // chunk lane      (all 64)
    const u64* p1 = src + base + 2 * (64 + lane);   // chunk 64+lane   (lanes 0-1)
    bool d0 = false, d1 = (lane >= 2);
    uint4v r0 = {0, 0, 0, 0}, r1 = {0, 0, 0, 0};
    int spin = 2;
    for (;;) {
        if (!d0) POLL16(r0, p0);
        if (!d1) POLL16(r1, p1);
        asm volatile("s_waitcnt vmcnt(0)" ::: "memory");
        __builtin_amdgcn_sched_barrier(0);          // no reg-only hoist past waitcnt
        if (!d0 && r0[1] == want && r0[3] == want) {
            *(float2*)&lds[base + 2 * lane] =
                make_float2(__uint_as_float(r0[0]), __uint_as_float(r0[2]));
            d0 = true;
        }
        if (!d1 && r1[1] == want && r1[3] == want) {
            *(float2*)&lds[base + 2 * (64 + lane)] =
                make_float2(__uint_as_float(r1[0]), __uint_as_float(r1[2]));
            d1 = true;
        }
        if (__all(d0 & d1)) break;
        if (--budget < 0) break;          // hang safety valve
        if (spin > 0) { --spin; continue; }
        __builtin_amdgcn_s_sleep(1);
    }
}

// Stage 264 pairs [base, base+264) via 132 x 16B polls.
__device__ __forceinline__ void stage264w(const u64* __restrict__ src, float* __restrict__ lds,
                                          int base, int lane, unsigned want, long long& budget) {
    const u64* p0 = src + base + 2 * lane;
    const u64* p1 = src + base + 2 * (64 + lane);
    const u64* p2 = src + base + 2 * (128 + lane);  // lanes 0-3
    bool d0 = false, d1 = false, d2 = (lane >= 4);
    uint4v r0 = {0, 0, 0, 0}, r1 = {0, 0, 0, 0}, r2 = {0, 0, 0, 0};
    int spin = 2;
    for (;;) {
        if (!d0) POLL16(r0, p0);
        if (!d1) POLL16(r1, p1);
        if (!d2) POLL16(r2, p2);
        asm volatile("s_waitcnt vmcnt(0)" ::: "memory");
        __builtin_amdgcn_sched_barrier(0);
        if (!d0 && r0[1] == want && r0[3] == want) {
            *(float2*)&lds[base + 2 * lane] =
                make_float2(__uint_as_float(r0[0]), __uint_as_float(r0[2]));
            d0 = true;
        }
        if (!d1 && r1[1] == want && r1[3] == want) {
            *(float2*)&lds[base + 2 * (64 + lane)] =
                make_float2(__uint_as_float(r1[0]), __uint_as_float(r1[2]));
            d1 = true;
        }
        if (!d2 && r2[1] == want && r2[3] == want) {
            *(float2*)&lds[base + 2 * (128 + lane)] =
                make_float2(__uint_as_float(r2[0]), __uint_as_float(r2[2]));
            d2 = true;
        }
        if (__all(d0 & d1 & d2)) break;
        if (--budget < 0) break;
        if (spin > 0) { --spin; continue; }
        __builtin_amdgcn_s_sleep(1);
    }
}

// ---------- fused 2-layer LSTM recurrence ----------
// r4 structure verbatim (verified 40.7ms). Sole change: L0's x[t] load hoisted
// to the top of the step loop (was after the butterfly inside k0==0) so the
// ~100-200cy L1/L2 hit overlaps phase P instead of sitting on the critical
// path between the butterfly and barrier B.
__global__ __launch_bounds__(1024, 4) void wn_fused(
    const float* __restrict__ x,
    const float* __restrict__ w_ih0, const float* __restrict__ w_hh0,
    const float* __restrict__ b_ih0, const float* __restrict__ b_hh0,
    const float* __restrict__ w_ih1, const float* __restrict__ w_hh1,
    const float* __restrict__ b_ih1, const float* __restrict__ b_hh1,
    u64* __restrict__ ring0,                  // [R0][HSU] (val,tag) of h1
    u64* __restrict__ ring1,                  // [16][HSU] (val,tag) of h2
    float* __restrict__ h2hist,               // [TT][HS] plain h2 for projection
    unsigned* __restrict__ l1prog)            // L1 WG0 progress (poison-tolerant)
{
    __shared__ float smem[4 * UP + 128];
    const int tid  = threadIdx.x;
    const int lane = tid & 63;
    const int w    = tid >> 6;                // wave 0..15

    for (int i = tid; i < 4 * UP + 128; i += 1024) smem[i] = 0.0f;

    if (blockIdx.x < NWG0) {
        // ========== layer 0 : 16 units/WG, rows = 4 gates x 16 units, 16 lanes/row ==========
        float* hbuf = smem;                   // [2][UP] staged h1
        float* gbuf = smem + 2 * UP;          // [2][64] gate pre-activations
        const int wg   = blockIdx.x;
        const int row  = tid >> 4;            // 0..63 = gate*16 + du
        const int k0   = tid & 15;
        const int gate = row >> 4;
        const int du   = row & 15;
        const int u    = wg * 16 + du;
        const bool real = (u < HH);
        const int wr   = gate * HH + (real ? u : 0);

        float wv[16][4], wt0 = 0.f, wt1 = 0.f;
#pragma unroll
        for (int m = 0; m < 16; ++m) {
            const int j = k0 * 4 + m * 64;
#pragma unroll
            for (int q = 0; q < 4; ++q)
                wv[m][q] = (real && j + q < HH) ? w_hh0[(size_t)wr * HH + j + q] : 0.0f;
        }
        {   const int j = 1024 + k0 * 2;
            wt0 = (real && j     < HH) ? w_hh0[(size_t)wr * HH + j]     : 0.0f;
            wt1 = (real && j + 1 < HH) ? w_hh0[(size_t)wr * HH + j + 1] : 0.0f; }
#pragma unroll
        for (int m = 0; m < 16; ++m)
#pragma unroll
            for (int q = 0; q < 4; ++q) asm volatile("" : "+v"(wv[m][q]));
        asm volatile("" : "+v"(wt0), "+v"(wt1));

        const float wx = real ? w_ih0[wr] : 0.0f;
        const float bs = real ? (b_ih0[wr] + b_hh0[wr]) : 0.0f;
        __syncthreads();

        long long budget = 20000000LL;
        float c_reg = 0.0f;
        for (int t = 0; t < TT; ++t) {
            // issue x[t] early (uniform addr -> 1 req/wave); pin so the
            // compiler can't sink it back into the k0==0 use after the butterfly
            float xt = x[t];
            asm volatile("" : "+v"(xt));
            // ---- phase P: epilogue+publish(t-1) [wave0] || poll+stage h1(t-1) [waves4-11] ----
            if (t > 0) {
                if (w == 0) {
                    const float* gl = gbuf + ((t - 1) & 1) * 64;
                    if (lane < 16) {
                        const float gi = gl[lane], gf = gl[16 + lane];
                        const float gg = gl[32 + lane], go = gl[48 + lane];
                        const float iv = sigmf(gi), fv = sigmf(gf), gv = tanhf(gg), ov = sigmf(go);
                        c_reg = fv * c_reg + iv * gv;
                        float hv = ov * tanhf(c_reg);
                        if (wg * 16 + lane >= HH) hv = 0.0f;
                        st_u64(ring0 + (size_t)((t - 1) & R0M) * HSU + wg * 16 + lane,
                               pack((unsigned)t, hv));      // coalesced 128B burst
                    }
                } else if (w >= 4 && w < 12) {
                    stage132w(ring0 + (size_t)((t - 1) & R0M) * HSU, hbuf + (t & 1) * UP,
                              (w - 4) * 132, lane, (unsigned)t, budget);
                } else if (w == 1 && lane == 0 && (t & 255) == 0) {
                    for (;;) {                 // ring backpressure: never lap L1
                        unsigned p = ld_u32(l1prog);
                        if ((int)t - (int)p < R0 - 256) break;
                        if (--budget < 0) break;
                        __builtin_amdgcn_s_sleep(32);
                    }
                }
            }
            __syncthreads();                   // A: stage visible
            const float* hb = hbuf + (t & 1) * UP;
            float acc = 0.0f;
#pragma unroll
            for (int m = 0; m < 16; ++m) {
                const float4 hv = *(const float4*)&hb[k0 * 4 + m * 64];
                acc = fmaf(wv[m][0], hv.x, acc);
                acc = fmaf(wv[m][1], hv.y, acc);
                acc = fmaf(wv[m][2], hv.z, acc);
                acc = fmaf(wv[m][3], hv.w, acc);
            }
            {   const float2 hv = *(const float2*)&hb[1024 + k0 * 2];
                acc = fmaf(wt0, hv.x, acc);
                acc = fmaf(wt1, hv.y, acc); }
#pragma unroll
            for (int off = 1; off < 16; off <<= 1) acc += __shfl_xor(acc, off);
            if (k0 == 0) gbuf[(t & 1) * 64 + row] = fmaf(xt, wx, acc) + bs;
            __syncthreads();                   // B: gates visible for next P
        }
        // final epilogue+publish for t = TT-1
        if (w == 0 && lane < 16) {
            const float* gl = gbuf + ((TT - 1) & 1) * 64;
            const float gi = gl[lane], gf = gl[16 + lane];
            const float gg = gl[32 + lane], go = gl[48 + lane];
            const float iv = sigmf(gi), fv = sigmf(gf), gv = tanhf(gg), ov = sigmf(go);
            c_reg = fv * c_reg + iv * gv;
            float hv = ov * tanhf(c_reg);
            if (wg * 16 + lane >= HH) hv = 0.0f;
            st_u64(ring0 + (size_t)((TT - 1) & R0M) * HSU + wg * 16 + lane,
                   pack((unsigned)TT, hv));
        }
    } else {
        // ========== layer 1 : 8 units/WG, rows = 4 gates x 8 units, 32 lanes/row ==========
        float* abuf = smem;                   // [2][UP] h1[t]
        float* bbuf = smem + 2 * UP;          // [2][UP] h2[t-1]
        float* gbuf = smem + 4 * UP;          // [2][32]
        const int wg   = blockIdx.x - NWG0;   // 0..131
        const int row  = tid >> 5;            // 0..31 = gate*8 + du
        const int k0   = tid & 31;
        const int gate = row >> 3;
        const int du   = row & 7;
        const int u    = wg * 8 + du;
        const bool real = (u < HH);
        const int wr   = gate * HH + (real ? u : 0);

        float wiv[8][4], whv[8][4], wit = 0.f, wht = 0.f;
#pragma unroll
        for (int m = 0; m < 8; ++m) {
            const int j = k0 * 4 + m * 128;
#pragma unroll
            for (int q = 0; q < 4; ++q) {
                const bool inb = real && (j + q < HH);
                wiv[m][q] = inb ? w_ih1[(size_t)wr * HH + j + q] : 0.0f;
                whv[m][q] = inb ? w_hh1[(size_t)wr * HH + j + q] : 0.0f;
            }
        }
        {   const int j = 1024 + k0;
            wit = (real && j < HH) ? w_ih1[(size_t)wr * HH + j] : 0.0f;
            wht = (real && j < HH) ? w_hh1[(size_t)wr * HH + j] : 0.0f; }
#pragma unroll
        for (int m = 0; m < 8; ++m)
#pragma unroll
            for (int q = 0; q < 4; ++q) {
                asm volatile("" : "+v"(wiv[m][q]));
                asm volatile("" : "+v"(whv[m][q]));
            }
        asm volatile("" : "+v"(wit), "+v"(wht));
        const float bs = real ? (b_ih1[wr] + b_hh1[wr]) : 0.0f;
        __syncthreads();

        long long budget = 20000000LL;
        float c_reg = 0.0f;
        for (int t = 0; t < TT; ++t) {
            // ---- phase P: epilogue(t-1) [wave0] || stage h2(t-1) [w4-11] || stage h1(t) [w12-15] ----
            if (w == 0) {
                if (t > 0) {
                    const float* gl = gbuf + ((t - 1) & 1) * 32;
                    if (lane < 8) {
                        const float gi = gl[lane], gf = gl[8 + lane];
                        const float gg = gl[16 + lane], go = gl[24 + lane];
                        const float iv = sigmf(gi), fv = sigmf(gf), gv = tanhf(gg), ov = sigmf(go);
                        c_reg = fv * c_reg + iv * gv;
                        float hv = ov * tanhf(c_reg);
                        if (wg * 8 + lane >= HH) hv = 0.0f;
                        st_u64(ring1 + (size_t)((t - 1) & R1M) * HSU + wg * 8 + lane,
                               pack((unsigned)t, hv));     // coalesced 64B burst
                        h2hist[(size_t)(t - 1) * HS + wg * 8 + lane] = hv;
                    }
                }
            } else if (w >= 4 && w < 12) {
                if (t > 0)
                    stage132w(ring1 + (size_t)((t - 1) & R1M) * HSU, bbuf + (t & 1) * UP,
                              (w - 4) * 132, lane, (unsigned)t, budget);
            } else if (w >= 12) {
                stage264w(ring0 + (size_t)(t & R0M) * HSU, abuf + (t & 1) * UP,
                          (w - 12) * 264, lane, (unsigned)(t + 1), budget);
            }
            __syncthreads();                   // A
            const float* ab = abuf + (t & 1) * UP;
            const float* bb = bbuf + (t & 1) * UP;
            float acc = 0.0f;
#pragma unroll
            for (int m = 0; m < 8; ++m) {
                const float4 ha = *(const float4*)&ab[k0 * 4 + m * 128];
                const float4 hb2 = *(const float4*)&bb[k0 * 4 + m * 128];
                acc = fmaf(wiv[m][0], ha.x, acc);
                acc = fmaf(wiv[m][1], ha.y, acc);
                acc = fmaf(wiv[m][2], ha.z, acc);
                acc = fmaf(wiv[m][3], ha.w, acc);
                acc = fmaf(whv[m][0], hb2.x, acc);
                acc = fmaf(whv[m][1], hb2.y, acc);
                acc = fmaf(whv[m][2], hb2.z, acc);
                acc = fmaf(whv[m][3], hb2.w, acc);
            }
            acc = fmaf(wit, ab[1024 + k0], acc);
            acc = fmaf(wht, bb[1024 + k0], acc);
#pragma unroll
            for (int off = 1; off < 32; off <<= 1) acc += __shfl_xor(acc, off);
            if (k0 == 0) gbuf[(t & 1) * 32 + row] = acc + bs;
            __syncthreads();                   // B
            if (w == 1 && lane == 0 && wg == 0 && (t & 255) == 255)
                st_u32(l1prog, (unsigned)(t + 1));        // backpressure progress
        }
        // final epilogue for t = TT-1
        if (w == 0 && lane < 8) {
            const float* gl = gbuf + ((TT - 1) & 1) * 32;
            const float gi = gl[lane], gf = gl[8 + lane];
            const float gg = gl[16 + lane], go = gl[24 + lane];
            const float iv = sigmf(gi), fv = sigmf(gf), gv = tanhf(gg), ov = sigmf(go);
            c_reg = fv * c_reg + iv * gv;
            float hv = ov * tanhf(c_reg);
            if (wg * 8 + lane >= HH) hv = 0.0f;
            h2hist[(size_t)(TT - 1) * HS + wg * 8 + lane] = hv;
        }
    }
}

// ---------- final projection: out[t] = lin_w . h2[t] + lin_b ----------
__global__ __launch_bounds__(256) void wn_proj(
    const float* __restrict__ h2,
    const float* __restrict__ lin_w,
    const float* __restrict__ lin_b,
    float* __restrict__ out)
{
    const int lane = threadIdx.x & 63;
    const int wv   = threadIdx.x >> 6;
    const int t    = blockIdx.x * 4 + wv;
    const float* hp = h2 + (size_t)t * HS;
    float acc = 0.0f;
#pragma unroll
    for (int m = 0; m < 4; ++m) {
        const int j = lane * 4 + m * 256;        // covers [0,1024)
        const float4 h4 = *(const float4*)(hp + j);
        const float4 w4 = *(const float4*)(lin_w + j);
        acc += h4.x * w4.x + h4.y * w4.y + h4.z * w4.z + h4.w * w4.w;
    }
    if (lane == 0) {
#pragma unroll
        for (int j = 1024; j < HH; ++j) acc += hp[j] * lin_w[j];
    }
#pragma unroll
    for (int off = 1; off < 64; off <<= 1) acc += __shfl_xor(acc, off);
    if (lane == 0) out[t] = acc + lin_b[0];
}

extern "C" void kernel_launch(void* const* d_in, const int* in_sizes, int n_in,
                              void* d_out, int out_size, void* d_ws, size_t ws_size,
                              hipStream_t stream) {
    const float* x     = (const float*)d_in[0];
    const float* w_ih0 = (const float*)d_in[1];
    const float* w_hh0 = (const float*)d_in[2];
    const float* b_ih0 = (const float*)d_in[3];
    const float* b_hh0 = (const float*)d_in[4];
    const float* w_ih1 = (const float*)d_in[5];
    const float* w_hh1 = (const float*)d_in[6];
    const float* b_ih1 = (const float*)d_in[7];
    const float* b_hh1 = (const float*)d_in[8];
    const float* lin_w = (const float*)d_in[9];
    const float* lin_b = (const float*)d_in[10];
    float* out = (float*)d_out;

    char* ws = (char*)d_ws;
    const size_t R0B = (size_t)R0 * HSU * 8;        //  8,650,752
    const size_t R1B = (size_t)16 * HSU * 8;        //    135,168
    const size_t H2B = (size_t)TT * HS * 4;         // 69,206,016
    u64* ring0 = (u64*)(ws);
    u64* ring1 = (u64*)(ws + R0B);
    float* h2hist = (float*)(ws + R0B + R1B);
    unsigned* l1prog = (unsigned*)(ws + R0B + R1B + H2B);
    // No init kernel: 0xAA poison never matches any tag (1..16384), and the
    // poisoned l1prog reads as negative -> L0 throttles until L1 publishes.

    wn_fused<<<NWGT, 1024, 0, stream>>>(x, w_ih0, w_hh0, b_ih0, b_hh0,
                                        w_ih1, w_hh1, b_ih1, b_hh1,
                                        ring0, ring1, h2hist, l1prog);
    wn_proj<<<TT / 4, 256, 0, stream>>>(h2hist, lin_w, lin_b, out);
}

// Round 10
// 40482.620 us; speedup vs baseline: 2.0275x; 1.0025x over previous
//
#include <hip/hip_runtime.h>
#include <math.h>

// Problem constants
#define HH    1028        // real hidden size
#define TT    16384       // timesteps
#define UP    1056        // padded hidden (= 16*66 = 8*132)
#define HSU   1056        // (val,tag) u64 pairs per ring row
#define HS    1056        // floats per h2 history row
#define NWG0  66          // layer-0 WGs, 16 units each
#define NWG1  132         // layer-1 WGs, 8 units each
#define NWGT  (NWG0 + NWG1)
#define R0    1024        // h1 ring depth
#define R0M   (R0 - 1)
#define R1M   15          // h2 ring depth 16

typedef unsigned long long u64;
typedef unsigned int uint4v __attribute__((ext_vector_type(4)));

// ---------- MALL-coherent primitives ----------
__device__ __forceinline__ u64 ld_u64(const u64* p) {
    return __hip_atomic_load(p, __ATOMIC_RELAXED, __HIP_MEMORY_SCOPE_AGENT);
}
__device__ __forceinline__ void st_u64(u64* p, u64 v) {
    __hip_atomic_store(p, v, __ATOMIC_RELAXED, __HIP_MEMORY_SCOPE_AGENT);
}
__device__ __forceinline__ unsigned ld_u32(const unsigned* p) {
    return __hip_atomic_load(p, __ATOMIC_RELAXED, __HIP_MEMORY_SCOPE_AGENT);
}
__device__ __forceinline__ void st_u32(unsigned* p, unsigned v) {
    __hip_atomic_store(p, v, __ATOMIC_RELAXED, __HIP_MEMORY_SCOPE_AGENT);
}
__device__ __forceinline__ float sigmf(float x) { return 1.0f / (1.0f + expf(-x)); }
__device__ __forceinline__ u64 pack(unsigned tag, float v) {
    return ((u64)tag << 32) | (u64)__float_as_uint(v);
}

// 16B coherent poll load: two (val,tag) pairs per request (r4-verified win).
#define POLL16(dst, ptr) \
    asm volatile("global_load_dwordx4 %0, %1, off sc0 sc1" : "=v"(dst) : "v"(ptr))

// Stage 132 (val,tag) pairs [base, base+132) into LDS via 66 x 16B polls.
__device__ __forceinline__ void stage132w(const u64* __restrict__ src, float* __restrict__ lds,
                                          int base, int lane, unsigned want, long long& budget) {
    const u64* p0 = src + base + 2 * lane;          // chunk lane      (all 64)
    const u64* p1 = src + base + 2 * (64 + lane);   // chunk 64+lane   (lanes 0-1)
    bool d0 = false, d1 = (lane >= 2);
    uint4v r0 = {0, 0, 0, 0}, r1 = {0, 0, 0, 0};
    int spin = 2;
    for (;;) {
        if (!d0) POLL16(r0, p0);
        if (!d1) POLL16(r1, p1);
        asm volatile("s_waitcnt vmcnt(0)" ::: "memory");
        __builtin_amdgcn_sched_barrier(0);          // no reg-only hoist past waitcnt
        if (!d0 && r0[1] == want && r0[3] == want) {
            *(float2*)&lds[base + 2 * lane] =
                make_float2(__uint_as_float(r0[0]), __uint_as_float(r0[2]));
            d0 = true;
        }
        if (!d1 && r1[1] == want && r1[3] == want) {
            *(float2*)&lds[base + 2 * (64 + lane)] =
                make_float2(__uint_as_float(r1[0]), __uint_as_float(r1[2]));
            d1 = true;
        }
        if (__all(d0 & d1)) break;
        if (--budget < 0) break;          // hang safety valve
        if (spin > 0) { --spin; continue; }
        __builtin_amdgcn_s_sleep(1);
    }
}

// Stage 264 pairs [base, base+264) via 132 x 16B polls.
__device__ __forceinline__ void stage264w(const u64* __restrict__ src, float* __restrict__ lds,
                                          int base, int lane, unsigned want, long long& budget) {
    const u64* p0 = src + base + 2 * lane;
    const u64* p1 = src + base + 2 * (64 + lane);
    const u64* p2 = src + base + 2 * (128 + lane);  // lanes 0-3
    bool d0 = false, d1 = false, d2 = (lane >= 4);
    uint4v r0 = {0, 0, 0, 0}, r1 = {0, 0, 0, 0}, r2 = {0, 0, 0, 0};
    int spin = 2;
    for (;;) {
        if (!d0) POLL16(r0, p0);
        if (!d1) POLL16(r1, p1);
        if (!d2) POLL16(r2, p2);
        asm volatile("s_waitcnt vmcnt(0)" ::: "memory");
        __builtin_amdgcn_sched_barrier(0);
        if (!d0 && r0[1] == want && r0[3] == want) {
            *(float2*)&lds[base + 2 * lane] =
                make_float2(__uint_as_float(r0[0]), __uint_as_float(r0[2]));
            d0 = true;
        }
        if (!d1 && r1[1] == want && r1[3] == want) {
            *(float2*)&lds[base + 2 * (64 + lane)] =
                make_float2(__uint_as_float(r1[0]), __uint_as_float(r1[2]));
            d1 = true;
        }
        if (!d2 && r2[1] == want && r2[3] == want) {
            *(float2*)&lds[base + 2 * (128 + lane)] =
                make_float2(__uint_as_float(r2[0]), __uint_as_float(r2[2]));
            d2 = true;
        }
        if (__all(d0 & d1 & d2)) break;
        if (--budget < 0) break;
        if (spin > 0) { --spin; continue; }
        __builtin_amdgcn_s_sleep(1);
    }
}

// ---------- fused 2-layer LSTM recurrence ----------
// r9 structure verbatim (verified 40.58ms). Sole change: gbuf transposed to
// unit-major [du*4+gate] so the epilogue reads all 4 gate sums with ONE
// ds_read_b128 instead of 4 scalar ds_read_b32 -> ~36cy off the serial
// critical path (barrier B -> epilogue -> publish). Bank patterns verified:
// readers 2-way aliased at worst (free), writers hit distinct banks.
__global__ __launch_bounds__(1024, 4) void wn_fused(
    const float* __restrict__ x,
    const float* __restrict__ w_ih0, const float* __restrict__ w_hh0,
    const float* __restrict__ b_ih0, const float* __restrict__ b_hh0,
    const float* __restrict__ w_ih1, const float* __restrict__ w_hh1,
    const float* __restrict__ b_ih1, const float* __restrict__ b_hh1,
    u64* __restrict__ ring0,                  // [R0][HSU] (val,tag) of h1
    u64* __restrict__ ring1,                  // [16][HSU] (val,tag) of h2
    float* __restrict__ h2hist,               // [TT][HS] plain h2 for projection
    unsigned* __restrict__ l1prog)            // L1 WG0 progress (poison-tolerant)
{
    __shared__ float smem[4 * UP + 128];
    const int tid  = threadIdx.x;
    const int lane = tid & 63;
    const int w    = tid >> 6;                // wave 0..15

    for (int i = tid; i < 4 * UP + 128; i += 1024) smem[i] = 0.0f;

    if (blockIdx.x < NWG0) {
        // ========== layer 0 : 16 units/WG, rows = 4 gates x 16 units, 16 lanes/row ==========
        float* hbuf = smem;                   // [2][UP] staged h1
        float* gbuf = smem + 2 * UP;          // [2][64] gate pre-activations, unit-major
        const int wg   = blockIdx.x;
        const int row  = tid >> 4;            // 0..63 = gate*16 + du
        const int k0   = tid & 15;
        const int gate = row >> 4;
        const int du   = row & 15;
        const int u    = wg * 16 + du;
        const bool real = (u < HH);
        const int wr   = gate * HH + (real ? u : 0);

        float wv[16][4], wt0 = 0.f, wt1 = 0.f;
#pragma unroll
        for (int m = 0; m < 16; ++m) {
            const int j = k0 * 4 + m * 64;
#pragma unroll
            for (int q = 0; q < 4; ++q)
                wv[m][q] = (real && j + q < HH) ? w_hh0[(size_t)wr * HH + j + q] : 0.0f;
        }
        {   const int j = 1024 + k0 * 2;
            wt0 = (real && j     < HH) ? w_hh0[(size_t)wr * HH + j]     : 0.0f;
            wt1 = (real && j + 1 < HH) ? w_hh0[(size_t)wr * HH + j + 1] : 0.0f; }
#pragma unroll
        for (int m = 0; m < 16; ++m)
#pragma unroll
            for (int q = 0; q < 4; ++q) asm volatile("" : "+v"(wv[m][q]));
        asm volatile("" : "+v"(wt0), "+v"(wt1));

        const float wx = real ? w_ih0[wr] : 0.0f;
        const float bs = real ? (b_ih0[wr] + b_hh0[wr]) : 0.0f;
        __syncthreads();

        long long budget = 20000000LL;
        float c_reg = 0.0f;
        for (int t = 0; t < TT; ++t) {
            // issue x[t] early (uniform addr -> 1 req/wave); pin so the
            // compiler can't sink it back into the k0==0 use after the butterfly
            float xt = x[t];
            asm volatile("" : "+v"(xt));
            // ---- phase P: epilogue+publish(t-1) [wave0] || poll+stage h1(t-1) [waves4-11] ----
            if (t > 0) {
                if (w == 0) {
                    const float* gl = gbuf + ((t - 1) & 1) * 64;
                    if (lane < 16) {
                        const float4 g4 = *(const float4*)&gl[lane * 4];   // i,f,g,o
                        const float iv = sigmf(g4.x), fv = sigmf(g4.y);
                        const float gv = tanhf(g4.z), ov = sigmf(g4.w);
                        c_reg = fv * c_reg + iv * gv;
                        float hv = ov * tanhf(c_reg);
                        if (wg * 16 + lane >= HH) hv = 0.0f;
                        st_u64(ring0 + (size_t)((t - 1) & R0M) * HSU + wg * 16 + lane,
                               pack((unsigned)t, hv));      // coalesced 128B burst
                    }
                } else if (w >= 4 && w < 12) {
                    stage132w(ring0 + (size_t)((t - 1) & R0M) * HSU, hbuf + (t & 1) * UP,
                              (w - 4) * 132, lane, (unsigned)t, budget);
                } else if (w == 1 && lane == 0 && (t & 255) == 0) {
                    for (;;) {                 // ring backpressure: never lap L1
                        unsigned p = ld_u32(l1prog);
                        if ((int)t - (int)p < R0 - 256) break;
                        if (--budget < 0) break;
                        __builtin_amdgcn_s_sleep(32);
                    }
                }
            }
            __syncthreads();                   // A: stage visible
            const float* hb = hbuf + (t & 1) * UP;
            float acc = 0.0f;
#pragma unroll
            for (int m = 0; m < 16; ++m) {
                const float4 hv = *(const float4*)&hb[k0 * 4 + m * 64];
                acc = fmaf(wv[m][0], hv.x, acc);
                acc = fmaf(wv[m][1], hv.y, acc);
                acc = fmaf(wv[m][2], hv.z, acc);
                acc = fmaf(wv[m][3], hv.w, acc);
            }
            {   const float2 hv = *(const float2*)&hb[1024 + k0 * 2];
                acc = fmaf(wt0, hv.x, acc);
                acc = fmaf(wt1, hv.y, acc); }
#pragma unroll
            for (int off = 1; off < 16; off <<= 1) acc += __shfl_xor(acc, off);
            if (k0 == 0) gbuf[(t & 1) * 64 + du * 4 + gate] = fmaf(xt, wx, acc) + bs;
            __syncthreads();                   // B: gates visible for next P
        }
        // final epilogue+publish for t = TT-1
        if (w == 0 && lane < 16) {
            const float* gl = gbuf + ((TT - 1) & 1) * 64;
            const float4 g4 = *(const float4*)&gl[lane * 4];
            const float iv = sigmf(g4.x), fv = sigmf(g4.y);
            const float gv = tanhf(g4.z), ov = sigmf(g4.w);
            c_reg = fv * c_reg + iv * gv;
            float hv = ov * tanhf(c_reg);
            if (wg * 16 + lane >= HH) hv = 0.0f;
            st_u64(ring0 + (size_t)((TT - 1) & R0M) * HSU + wg * 16 + lane,
                   pack((unsigned)TT, hv));
        }
    } else {
        // ========== layer 1 : 8 units/WG, rows = 4 gates x 8 units, 32 lanes/row ==========
        float* abuf = smem;                   // [2][UP] h1[t]
        float* bbuf = smem + 2 * UP;          // [2][UP] h2[t-1]
        float* gbuf = smem + 4 * UP;          // [2][32], unit-major
        const int wg   = blockIdx.x - NWG0;   // 0..131
        const int row  = tid >> 5;            // 0..31 = gate*8 + du
        const int k0   = tid & 31;
        const int gate = row >> 3;
        const int du   = row & 7;
        const int u    = wg * 8 + du;
        const bool real = (u < HH);
        const int wr   = gate * HH + (real ? u : 0);

        float wiv[8][4], whv[8][4], wit = 0.f, wht = 0.f;
#pragma unroll
        for (int m = 0; m < 8; ++m) {
            const int j = k0 * 4 + m * 128;
#pragma unroll
            for (int q = 0; q < 4; ++q) {
                const bool inb = real && (j + q < HH);
                wiv[m][q] = inb ? w_ih1[(size_t)wr * HH + j + q] : 0.0f;
                whv[m][q] = inb ? w_hh1[(size_t)wr * HH + j + q] : 0.0f;
            }
        }
        {   const int j = 1024 + k0;
            wit = (real && j < HH) ? w_ih1[(size_t)wr * HH + j] : 0.0f;
            wht = (real && j < HH) ? w_hh1[(size_t)wr * HH + j] : 0.0f; }
#pragma unroll
        for (int m = 0; m < 8; ++m)
#pragma unroll
            for (int q = 0; q < 4; ++q) {
                asm volatile("" : "+v"(wiv[m][q]));
                asm volatile("" : "+v"(whv[m][q]));
            }
        asm volatile("" : "+v"(wit), "+v"(wht));
        const float bs = real ? (b_ih1[wr] + b_hh1[wr]) : 0.0f;
        __syncthreads();

        long long budget = 20000000LL;
        float c_reg = 0.0f;
        for (int t = 0; t < TT; ++t) {
            // ---- phase P: epilogue(t-1) [wave0] || stage h2(t-1) [w4-11] || stage h1(t) [w12-15] ----
            if (w == 0) {
                if (t > 0) {
                    const float* gl = gbuf + ((t - 1) & 1) * 32;
                    if (lane < 8) {
                        const float4 g4 = *(const float4*)&gl[lane * 4];   // i,f,g,o
                        const float iv = sigmf(g4.x), fv = sigmf(g4.y);
                        const float gv = tanhf(g4.z), ov = sigmf(g4.w);
                        c_reg = fv * c_reg + iv * gv;
                        float hv = ov * tanhf(c_reg);
                        if (wg * 8 + lane >= HH) hv = 0.0f;
                        st_u64(ring1 + (size_t)((t - 1) & R1M) * HSU + wg * 8 + lane,
                               pack((unsigned)t, hv));     // coalesced 64B burst
                        h2hist[(size_t)(t - 1) * HS + wg * 8 + lane] = hv;
                    }
                }
            } else if (w >= 4 && w < 12) {
                if (t > 0)
                    stage132w(ring1 + (size_t)((t - 1) & R1M) * HSU, bbuf + (t & 1) * UP,
                              (w - 4) * 132, lane, (unsigned)t, budget);
            } else if (w >= 12) {
                stage264w(ring0 + (size_t)(t & R0M) * HSU, abuf + (t & 1) * UP,
                          (w - 12) * 264, lane, (unsigned)(t + 1), budget);
            }
            __syncthreads();                   // A
            const float* ab = abuf + (t & 1) * UP;
            const float* bb = bbuf + (t & 1) * UP;
            float acc = 0.0f;
#pragma unroll
            for (int m = 0; m < 8; ++m) {
                const float4 ha = *(const float4*)&ab[k0 * 4 + m * 128];
                const float4 hb2 = *(const float4*)&bb[k0 * 4 + m * 128];
                acc = fmaf(wiv[m][0], ha.x, acc);
                acc = fmaf(wiv[m][1], ha.y, acc);
                acc = fmaf(wiv[m][2], ha.z, acc);
                acc = fmaf(wiv[m][3], ha.w, acc);
                acc = fmaf(whv[m][0], hb2.x, acc);
                acc = fmaf(whv[m][1], hb2.y, acc);
                acc = fmaf(whv[m][2], hb2.z, acc);
                acc = fmaf(whv[m][3], hb2.w, acc);
            }
            acc = fmaf(wit, ab[1024 + k0], acc);
            acc = fmaf(wht, bb[1024 + k0], acc);
#pragma unroll
            for (int off = 1; off < 32; off <<= 1) acc += __shfl_xor(acc, off);
            if (k0 == 0) gbuf[(t & 1) * 32 + du * 4 + gate] = acc + bs;
            __syncthreads();                   // B
            if (w == 1 && lane == 0 && wg == 0 && (t & 255) == 255)
                st_u32(l1prog, (unsigned)(t + 1));        // backpressure progress
        }
        // final epilogue for t = TT-1
        if (w == 0 && lane < 8) {
            const float* gl = gbuf + ((TT - 1) & 1) * 32;
            const float4 g4 = *(const float4*)&gl[lane * 4];
            const float iv = sigmf(g4.x), fv = sigmf(g4.y);
            const float gv = tanhf(g4.z), ov = sigmf(g4.w);
            c_reg = fv * c_reg + iv * gv;
            float hv = ov * tanhf(c_reg);
            if (wg * 8 + lane >= HH) hv = 0.0f;
            h2hist[(size_t)(TT - 1) * HS + wg * 8 + lane] = hv;
        }
    }
}

// ---------- final projection: out[t] = lin_w . h2[t] + lin_b ----------
__global__ __launch_bounds__(256) void wn_proj(
    const float* __restrict__ h2,
    const float* __restrict__ lin_w,
    const float* __restrict__ lin_b,
    float* __restrict__ out)
{
    const int lane = threadIdx.x & 63;
    const int wv   = threadIdx.x >> 6;
    const int t    = blockIdx.x * 4 + wv;
    const float* hp = h2 + (size_t)t * HS;
    float acc = 0.0f;
#pragma unroll
    for (int m = 0; m < 4; ++m) {
        const int j = lane * 4 + m * 256;        // covers [0,1024)
        const float4 h4 = *(const float4*)(hp + j);
        const float4 w4 = *(const float4*)(lin_w + j);
        acc += h4.x * w4.x + h4.y * w4.y + h4.z * w4.z + h4.w * w4.w;
    }
    if (lane == 0) {
#pragma unroll
        for (int j = 1024; j < HH; ++j) acc += hp[j] * lin_w[j];
    }
#pragma unroll
    for (int off = 1; off < 64; off <<= 1) acc += __shfl_xor(acc, off);
    if (lane == 0) out[t] = acc + lin_b[0];
}

extern "C" void kernel_launch(void* const* d_in, const int* in_sizes, int n_in,
                              void* d_out, int out_size, void* d_ws, size_t ws_size,
                              hipStream_t stream) {
    const float* x     = (const float*)d_in[0];
    const float* w_ih0 = (const float*)d_in[1];
    const float* w_hh0 = (const float*)d_in[2];
    const float* b_ih0 = (const float*)d_in[3];
    const float* b_hh0 = (const float*)d_in[4];
    const float* w_ih1 = (const float*)d_in[5];
    const float* w_hh1 = (const float*)d_in[6];
    const float* b_ih1 = (const float*)d_in[7];
    const float* b_hh1 = (const float*)d_in[8];
    const float* lin_w = (const float*)d_in[9];
    const float* lin_b = (const float*)d_in[10];
    float* out = (float*)d_out;

    char* ws = (char*)d_ws;
    const size_t R0B = (size_t)R0 * HSU * 8;        //  8,650,752
    const size_t R1B = (size_t)16 * HSU * 8;        //    135,168
    const size_t H2B = (size_t)TT * HS * 4;         // 69,206,016
    u64* ring0 = (u64*)(ws);
    u64* ring1 = (u64*)(ws + R0B);
    float* h2hist = (float*)(ws + R0B + R1B);
    unsigned* l1prog = (unsigned*)(ws + R0B + R1B + H2B);
    // No init kernel: 0xAA poison never matches any tag (1..16384), and the
    // poisoned l1prog reads as negative -> L0 throttles until L1 publishes.

    wn_fused<<<NWGT, 1024, 0, stream>>>(x, w_ih0, w_hh0, b_ih0, b_hh0,
                                        w_ih1, w_hh1, b_ih1, b_hh1,
                                        ring0, ring1, h2hist, l1prog);
    wn_proj<<<TT / 4, 256, 0, stream>>>(h2hist, lin_w, lin_b, out);
}